// Round 7
// baseline (786.235 us; speedup 1.0000x reference)
//
#include <hip/hip_runtime.h>
#include <hip/hip_bf16.h>

typedef __bf16 bf16_t;
typedef __bf16 bf16x8 __attribute__((ext_vector_type(8)));
typedef float f32x4 __attribute__((ext_vector_type(4)));

#define B_    4
#define LQ_   13343
#define D_    256
#define H_    8
#define HD_   32
#define DFF_  2048
#define M_    (B_ * LQ_)   // 53372 tokens

// bijective XCD-chunk swizzle (m204): contiguous wgid ranges per XCD
__device__ __forceinline__ int xcd_swz(int orig, int nwg) {
  int q = nwg >> 3, r = nwg & 7;
  int xcd = orig & 7, idx = orig >> 3;
  return (xcd < r ? xcd * (q + 1) : r * (q + 1) + (xcd - r) * q) + idx;
}

#define BM 128
#define BN 128
#define BK 32

#define MODE_F32       0
#define MODE_BF16      2
#define MODE_BF16_RELU 3

__device__ __forceinline__ void gload_lds16(const void* g, void* l) {
  __builtin_amdgcn_global_load_lds(
      (const __attribute__((address_space(1))) void*)g,
      (__attribute__((address_space(3))) void*)l, 16, 0, 0);
}

// ---------------- GEMM: C = A[M,K] @ Bt[N,K]^T + bias (R6 structure) ----------------
template <int MODE, bool AF32>
__global__ __launch_bounds__(256) void gemm_bt(
    const void* __restrict__ Av, int lda,
    const bf16_t* __restrict__ Bt, int ldb,
    const float* __restrict__ bias,
    void* __restrict__ Cv, int ldc,
    int M, int N, int K)
{
  __shared__ alignas(16) bf16_t As[2][BM * BK];
  __shared__ alignas(16) bf16_t Bs[2][BN * BK];
  const int tid  = threadIdx.x;
  const int wave = tid >> 6, lane = tid & 63;
  const int nyb = (N + BN - 1) / BN;
  const int gid = xcd_swz(blockIdx.x, (int)gridDim.x);
  const int m0 = (gid / nyb) * BM;
  const int n0 = (gid - (gid / nyb) * nyb) * BN;
  const int wm = (wave & 1) * 64;
  const int wn = (wave >> 1) * 64;
  const int lrow = lane & 15;
  const int quad = lane >> 4;

  const int srow = wave * 16 + (lane >> 2);
  const int scol = (lane & 3) * 8;
  const bf16_t* Ab = (const bf16_t*)Av;
  const float*  Af = (const float*)Av;

  const int ar0 = min(m0 + srow,      M - 1);
  const int ar1 = min(m0 + srow + 64, M - 1);
  const int br0 = min(n0 + srow,      N - 1);
  const int br1 = min(n0 + srow + 64, N - 1);

  const int r0 = tid >> 2;
  const int kc = (tid & 3) * 8;
  const int arw0 = min(m0 + r0,      M - 1);
  const int arw1 = min(m0 + r0 + 64, M - 1);

  auto stage_async = [&](int ke, int buf) {
    if (!AF32) {
      gload_lds16(Ab + (size_t)ar0 * lda + ke + scol, &As[buf][wave * 512]);
      gload_lds16(Ab + (size_t)ar1 * lda + ke + scol, &As[buf][2048 + wave * 512]);
    }
    gload_lds16(Bt + (size_t)br0 * ldb + ke + scol, &Bs[buf][wave * 512]);
    gload_lds16(Bt + (size_t)br1 * ldb + ke + scol, &Bs[buf][2048 + wave * 512]);
  };

  if (AF32) {
    const f32x4* p0 = (const f32x4*)(Af + (size_t)arw0 * lda + kc);
    const f32x4* p1 = (const f32x4*)(Af + (size_t)arw1 * lda + kc);
    f32x4 u0 = p0[0], w0 = p0[1], u1 = p1[0], w1 = p1[1];
    bf16x8 a0, a1;
#pragma unroll
    for (int j = 0; j < 4; ++j) {
      a0[j] = (bf16_t)u0[j]; a0[j + 4] = (bf16_t)w0[j];
      a1[j] = (bf16_t)u1[j]; a1[j + 4] = (bf16_t)w1[j];
    }
    *(bf16x8*)(&As[0][r0 * BK + kc])        = a0;
    *(bf16x8*)(&As[0][(r0 + 64) * BK + kc]) = a1;
  }
  stage_async(0, 0);
  __syncthreads();

  f32x4 acc[4][4] = {};
  const int nkt = K / BK;
  for (int kt = 0; kt < nkt; ++kt) {
    const int cur = kt & 1, nxt = cur ^ 1;
    const bool more = (kt + 1) < nkt;
    f32x4 u0 = {}, w0 = {}, u1 = {}, w1 = {};
    if (more) {
      const int ke = (kt + 1) * BK;
      if (AF32) {
        const f32x4* p0 = (const f32x4*)(Af + (size_t)arw0 * lda + ke + kc);
        const f32x4* p1 = (const f32x4*)(Af + (size_t)arw1 * lda + ke + kc);
        u0 = p0[0]; w0 = p0[1]; u1 = p1[0]; w1 = p1[1];
      }
      stage_async(ke, nxt);
    }
    bf16x8 af[4], bfr[4];
#pragma unroll
    for (int i = 0; i < 4; ++i)
      af[i] = *(const bf16x8*)(&As[cur][(wm + i * 16 + lrow) * BK + quad * 8]);
#pragma unroll
    for (int j = 0; j < 4; ++j)
      bfr[j] = *(const bf16x8*)(&Bs[cur][(wn + j * 16 + lrow) * BK + quad * 8]);
#pragma unroll
    for (int i = 0; i < 4; ++i)
#pragma unroll
      for (int j = 0; j < 4; ++j)
        acc[i][j] = __builtin_amdgcn_mfma_f32_16x16x32_bf16(af[i], bfr[j], acc[i][j], 0, 0, 0);
    if (more && AF32) {
      bf16x8 a0, a1;
#pragma unroll
      for (int j = 0; j < 4; ++j) {
        a0[j] = (bf16_t)u0[j]; a0[j + 4] = (bf16_t)w0[j];
        a1[j] = (bf16_t)u1[j]; a1[j + 4] = (bf16_t)w1[j];
      }
      *(bf16x8*)(&As[nxt][r0 * BK + kc])        = a0;
      *(bf16x8*)(&As[nxt][(r0 + 64) * BK + kc]) = a1;
    }
    __syncthreads();
  }

  float*  Cf = (float*)Cv;
  bf16_t* Cb = (bf16_t*)Cv;
#pragma unroll
  for (int i = 0; i < 4; ++i) {
#pragma unroll
    for (int j = 0; j < 4; ++j) {
      int gn = n0 + wn + j * 16 + lrow;
      if (gn >= N) continue;
      float bv = bias ? bias[gn] : 0.f;
#pragma unroll
      for (int r = 0; r < 4; ++r) {
        int gm = m0 + wm + i * 16 + quad * 4 + r;
        if (gm >= M) continue;
        float v = acc[i][j][r] + bv;
        size_t ci = (size_t)gm * ldc + gn;
        if (MODE == MODE_F32)       Cf[ci] = v;
        else if (MODE == MODE_BF16) Cb[ci] = (bf16_t)v;
        else                        Cb[ci] = (bf16_t)(v > 0.f ? v : 0.f);
      }
    }
  }
}

// ---- merged offset+attn GEMM: A = (src+pos) inline (R6 structure) ----
__global__ __launch_bounds__(256) void gemm_qkv(
    const float* __restrict__ src, const float* __restrict__ pos,
    const bf16_t* __restrict__ Bt,     // wTqkv [480][256]
    const float* __restrict__ b_off, const float* __restrict__ b_attn,
    bf16_t* __restrict__ offb, float* __restrict__ attnb)
{
  __shared__ alignas(16) bf16_t As[2][BM * BK];
  __shared__ alignas(16) bf16_t Bs[2][BN * BK];
  const int tid  = threadIdx.x;
  const int wave = tid >> 6, lane = tid & 63;
  const int gid = xcd_swz(blockIdx.x, (int)gridDim.x);
  const int m0 = (gid >> 2) * BM;
  const int n0 = (gid & 3) * BN;
  const int wm = (wave & 1) * 64;
  const int wn = (wave >> 1) * 64;
  const int lrow = lane & 15;
  const int quad = lane >> 4;
  const int N = 480;

  const int srow = wave * 16 + (lane >> 2);
  const int scol = (lane & 3) * 8;
  const int br0 = min(n0 + srow,      N - 1);
  const int br1 = min(n0 + srow + 64, N - 1);
  const int r0 = tid >> 2;
  const int kc = (tid & 3) * 8;
  const int arw0 = min(m0 + r0,      M_ - 1);
  const int arw1 = min(m0 + r0 + 64, M_ - 1);

  auto stageB = [&](int ke, int buf) {
    gload_lds16(Bt + (size_t)br0 * 256 + ke + scol, &Bs[buf][wave * 512]);
    gload_lds16(Bt + (size_t)br1 * 256 + ke + scol, &Bs[buf][2048 + wave * 512]);
  };
  auto loadA = [&](int ke, f32x4& u0, f32x4& w0, f32x4& u1, f32x4& w1) {
    const f32x4* s0 = (const f32x4*)(src + (size_t)arw0 * 256 + ke + kc);
    const f32x4* p0 = (const f32x4*)(pos + (size_t)arw0 * 256 + ke + kc);
    const f32x4* s1 = (const f32x4*)(src + (size_t)arw1 * 256 + ke + kc);
    const f32x4* p1 = (const f32x4*)(pos + (size_t)arw1 * 256 + ke + kc);
    u0 = s0[0] + p0[0]; w0 = s0[1] + p0[1];
    u1 = s1[0] + p1[0]; w1 = s1[1] + p1[1];
  };
  auto writeA = [&](int buf, f32x4 u0, f32x4 w0, f32x4 u1, f32x4 w1) {
    bf16x8 a0, a1;
#pragma unroll
    for (int j = 0; j < 4; ++j) {
      a0[j] = (bf16_t)u0[j]; a0[j + 4] = (bf16_t)w0[j];
      a1[j] = (bf16_t)u1[j]; a1[j + 4] = (bf16_t)w1[j];
    }
    *(bf16x8*)(&As[buf][r0 * BK + kc])        = a0;
    *(bf16x8*)(&As[buf][(r0 + 64) * BK + kc]) = a1;
  };

  { f32x4 u0, w0, u1, w1; loadA(0, u0, w0, u1, w1); writeA(0, u0, w0, u1, w1); }
  stageB(0, 0);
  __syncthreads();

  f32x4 acc[4][4] = {};
  for (int kt = 0; kt < 8; ++kt) {
    const int cur = kt & 1, nxt = cur ^ 1;
    const bool more = kt < 7;
    f32x4 u0 = {}, w0 = {}, u1 = {}, w1 = {};
    if (more) { loadA((kt + 1) * BK, u0, w0, u1, w1); stageB((kt + 1) * BK, nxt); }
    bf16x8 af[4], bfr[4];
#pragma unroll
    for (int i = 0; i < 4; ++i)
      af[i] = *(const bf16x8*)(&As[cur][(wm + i * 16 + lrow) * BK + quad * 8]);
#pragma unroll
    for (int j = 0; j < 4; ++j)
      bfr[j] = *(const bf16x8*)(&Bs[cur][(wn + j * 16 + lrow) * BK + quad * 8]);
#pragma unroll
    for (int i = 0; i < 4; ++i)
#pragma unroll
      for (int j = 0; j < 4; ++j)
        acc[i][j] = __builtin_amdgcn_mfma_f32_16x16x32_bf16(af[i], bfr[j], acc[i][j], 0, 0, 0);
    if (more) writeA(nxt, u0, w0, u1, w1);
    __syncthreads();
  }

#pragma unroll
  for (int i = 0; i < 4; ++i) {
#pragma unroll
    for (int j = 0; j < 4; ++j) {
      int gn = n0 + wn + j * 16 + lrow;
      if (gn >= N) continue;
      float bv = (gn < 320) ? b_off[gn] : b_attn[gn - 320];
#pragma unroll
      for (int r = 0; r < 4; ++r) {
        int gm = m0 + wm + i * 16 + quad * 4 + r;
        if (gm >= M_) continue;
        float v = acc[i][j][r] + bv;
        if (gn < 320) offb[(size_t)gm * 320 + gn] = (bf16_t)v;
        else          attnb[(size_t)gm * 160 + gn - 320] = v;
      }
    }
  }
}

// ---------------- fused FFN: reg-held weights, 2 barriers/hc, swizzled LDS ----
// Weights are per-wave-private -> loaded global->VGPR (L2-hot, XCD swizzle),
// NO barrier in MFMA phases. xs/hs XOR-swizzled (byte ^= (row&7)<<4): reg-staged
// both sides -> conflict-free reads. Accumulation order & h rounding identical
// to unfused -> bit-identical output.
#define SWZ(row, byte) ((byte) ^ (((row) & 7) << 4))
__global__ __launch_bounds__(256, 3) void k_ffn(
    const bf16_t* __restrict__ x,     // [M,256] bf16 (xbuf)
    const bf16_t* __restrict__ w1t,   // [2048][256]
    const float* __restrict__ bl1,    // [2048]
    const bf16_t* __restrict__ w2t,   // [256][2048]
    float* __restrict__ outf)         // [M,256] f32
{
  __shared__ alignas(16) bf16_t xs[8][64 * 32];   // 32 KB, swizzled
  __shared__ alignas(16) bf16_t hs[4][64 * 32];   // 16 KB, swizzled
  const int tid  = threadIdx.x;
  const int wave = tid >> 6, lane = tid & 63;
  const int lrow = lane & 15, quad = lane >> 4;
  const int m0 = xcd_swz(blockIdx.x, (int)gridDim.x) * 64;
  const int srow = lane >> 2;            // 0..15
  const int scol = (lane & 3) * 8;       // 0,8,16,24
  const int wc0 = wave * 64;

  // stage x (reg -> swizzled LDS), resident for whole kernel
  {
    const int row = wave * 16 + srow;
    const int gr = min(m0 + row, M_ - 1);
    const int wb = SWZ(row, row * 64 + scol * 2);
#pragma unroll
    for (int c = 0; c < 8; ++c) {
      bf16x8 v = *(const bf16x8*)(x + (size_t)gr * 256 + c * 32 + scol);
      *(bf16x8*)((char*)&xs[c][0] + wb) = v;
    }
  }

  // per-lane weight fragment pointers (B-operand rows for this wave)
  const bf16_t* w1r0 = w1t + (size_t)(wave * 32 + lrow) * 256 + quad * 8;
  const bf16_t* w1r1 = w1t + (size_t)(wave * 32 + 16 + lrow) * 256 + quad * 8;
  const bf16_t* w2r0 = w2t + (size_t)(wc0 + lrow) * 2048 + quad * 8;
  const bf16_t* w2r1 = w2r0 + (size_t)16 * 2048;
  const bf16_t* w2r2 = w2r0 + (size_t)32 * 2048;
  const bf16_t* w2r3 = w2r0 + (size_t)48 * 2048;

  __syncthreads();   // xs staged

  f32x4 cacc[4][4] = {};
  for (int hc = 0; hc < 16; ++hc) {
    const float b0 = bl1[hc * 128 + wave * 32 + lrow];
    const float b1 = bl1[hc * 128 + wave * 32 + 16 + lrow];
    const size_t w1off = (size_t)hc * 128 * 256;
    f32x4 hacc[4][2] = {};
#pragma unroll
    for (int kt = 0; kt < 8; ++kt) {       // no barriers: weights in regs
      bf16x8 bf0 = *(const bf16x8*)(w1r0 + w1off + kt * 32);
      bf16x8 bf1 = *(const bf16x8*)(w1r1 + w1off + kt * 32);
      bf16x8 af[4];
#pragma unroll
      for (int i = 0; i < 4; ++i) {
        const int row = i * 16 + lrow;
        af[i] = *(const bf16x8*)((char*)&xs[kt][0] + SWZ(row, row * 64 + quad * 16));
      }
#pragma unroll
      for (int i = 0; i < 4; ++i) {
        hacc[i][0] = __builtin_amdgcn_mfma_f32_16x16x32_bf16(af[i], bf0, hacc[i][0], 0, 0, 0);
        hacc[i][1] = __builtin_amdgcn_mfma_f32_16x16x32_bf16(af[i], bf1, hacc[i][1], 0, 0, 0);
      }
    }
    __syncthreads();   // prev hc's hs readers done
#pragma unroll
    for (int i = 0; i < 4; ++i)
#pragma unroll
      for (int j = 0; j < 2; ++j) {
        const float bb = j ? b1 : b0;
#pragma unroll
        for (int r = 0; r < 4; ++r) {
          float v = hacc[i][j][r] + bb;
          const int row = i * 16 + quad * 4 + r;
          *(bf16_t*)((char*)&hs[wave][0] + SWZ(row, row * 64 + (j * 16 + lrow) * 2)) =
              (bf16_t)(v > 0.f ? v : 0.f);
        }
      }
    __syncthreads();   // hs visible
    const size_t w2off = (size_t)hc * 128;
#pragma unroll
    for (int kt2 = 0; kt2 < 4; ++kt2) {    // no barriers
      bf16x8 bf2[4];
      bf2[0] = *(const bf16x8*)(w2r0 + w2off + kt2 * 32);
      bf2[1] = *(const bf16x8*)(w2r1 + w2off + kt2 * 32);
      bf2[2] = *(const bf16x8*)(w2r2 + w2off + kt2 * 32);
      bf2[3] = *(const bf16x8*)(w2r3 + w2off + kt2 * 32);
      bf16x8 af2[4];
#pragma unroll
      for (int i = 0; i < 4; ++i) {
        const int row = i * 16 + lrow;
        af2[i] = *(const bf16x8*)((char*)&hs[kt2][0] + SWZ(row, row * 64 + quad * 16));
      }
#pragma unroll
      for (int i = 0; i < 4; ++i)
#pragma unroll
        for (int j = 0; j < 4; ++j)
          cacc[i][j] = __builtin_amdgcn_mfma_f32_16x16x32_bf16(af2[i], bf2[j], cacc[i][j], 0, 0, 0);
    }
  }

#pragma unroll
  for (int i = 0; i < 4; ++i)
#pragma unroll
    for (int j = 0; j < 4; ++j)
#pragma unroll
      for (int r = 0; r < 4; ++r) {
        int gm = m0 + i * 16 + quad * 4 + r;
        if (gm < M_) outf[(size_t)gm * 256 + wc0 + j * 16 + lrow] = cacc[i][j][r];
      }
}

// ---------------- small kernels ----------------
__global__ __launch_bounds__(256) void k_transpose_all(
    const float* __restrict__ i0, const float* __restrict__ i1,
    const float* __restrict__ i2, const float* __restrict__ i3,
    const float* __restrict__ i4, const float* __restrict__ i5,
    bf16_t* __restrict__ o0, bf16_t* __restrict__ o1, bf16_t* __restrict__ o2,
    bf16_t* __restrict__ o3, bf16_t* __restrict__ o4, bf16_t* __restrict__ o5)
{
  int bid = blockIdx.x;
  const float* in; bf16_t* out; int K, N, txn;
  if (bid < 80)        { in = i0; out = o0; K = 256;  N = 320;  txn = 10; }
  else if (bid < 120)  { in = i1; out = o1; K = 256;  N = 160;  bid -= 80;  txn = 5; }
  else if (bid < 184)  { in = i2; out = o2; K = 256;  N = 256;  bid -= 120; txn = 8; }
  else if (bid < 248)  { in = i3; out = o3; K = 256;  N = 256;  bid -= 184; txn = 8; }
  else if (bid < 760)  { in = i4; out = o4; K = 256;  N = 2048; bid -= 248; txn = 64; }
  else                 { in = i5; out = o5; K = 2048; N = 256;  bid -= 760; txn = 8; }
  const int bx = bid % txn, by = bid / txn;
  __shared__ float tile[32][33];
  const int k0 = by * 32, n0 = bx * 32;
  const int tx = threadIdx.x & 31, ty = threadIdx.x >> 5;
#pragma unroll
  for (int r = ty; r < 32; r += 8)
    tile[r][tx] = in[(size_t)(k0 + r) * N + n0 + tx];
  __syncthreads();
#pragma unroll
  for (int r = ty; r < 32; r += 8)
    out[(size_t)(n0 + r) * K + k0 + tx] = (bf16_t)tile[tx][r];
}

// 8 queries/block; 32 threads/query; fused in-LDS softmax; XCD swizzle.
__global__ __launch_bounds__(256) void k_sample(
    const bf16_t* __restrict__ value,   // [B*LQ, 256]
    const bf16_t* __restrict__ off,     // [M, 320]
    const float* __restrict__ attn,     // [M, 160] RAW logits
    const float* __restrict__ rp,       // [M, 10]
    bf16_t* __restrict__ core)          // [M, 256]
{
  const int Wl[5] = {100, 50, 25, 13, 7};
  const int st[5] = {0, 10000, 12500, 13125, 13294};
  __shared__ alignas(16) bf16_t s_off[8][320];
  __shared__ alignas(16) float  s_attn[8][160];
  __shared__ float s_rp[8][10];
  const int t = threadIdx.x;
  const int bq0 = xcd_swz(blockIdx.x, (int)gridDim.x) * 8;
  for (int i = t; i < 320; i += 256) {
    int q = i / 40, e = i - q * 40;
    if (bq0 + q < M_) {
      *(bf16x8*)&s_off[q][e * 8] = *(const bf16x8*)(off + (size_t)(bq0 + q) * 320 + e * 8);
      *(f32x4*)&s_attn[q][e * 4] = *(const f32x4*)(attn + (size_t)(bq0 + q) * 160 + e * 4);
    }
  }
  if (t < 80) {
    int q = t / 10, e = t - q * 10;
    if (bq0 + q < M_) s_rp[q][e] = rp[(size_t)(bq0 + q) * 10 + e];
  }
  __syncthreads();
  if (t < 64) {
    float* p = &s_attn[t >> 3][(t & 7) * 20];
    float mx = p[0];
#pragma unroll
    for (int i = 1; i < 20; ++i) mx = fmaxf(mx, p[i]);
    float e[20], sum = 0.f;
#pragma unroll
    for (int i = 0; i < 20; ++i) { e[i] = expf(p[i] - mx); sum += e[i]; }
    float inv = 1.f / sum;
#pragma unroll
    for (int i = 0; i < 20; ++i) p[i] = e[i] * inv;
  }
  __syncthreads();

  const int wq = t >> 5, s = t & 31;
  const int h = s >> 2, d0 = (s & 3) * 8;
  const int bq = bq0 + wq;
  if (bq >= M_) return;
  const int b = bq / LQ_;
  const bf16_t* vbase = value + ((size_t)b * LQ_) * 256 + h * 32 + d0;
  float acc[8] = {};
#pragma unroll
  for (int lvl = 0; lvl < 5; ++lvl) {
    const float W = (float)Wl[lvl];
    const float rx = s_rp[wq][lvl * 2], ry = s_rp[wq][lvl * 2 + 1];
#pragma unroll
    for (int p = 0; p < 4; ++p) {
      const int base = (h * 5 + lvl) * 4 + p;
      float px = rx * W + (float)s_off[wq][base * 2]     - 0.5f;
      float py = ry * W + (float)s_off[wq][base * 2 + 1] - 0.5f;
      float aw = s_attn[wq][h * 20 + lvl * 4 + p];
      float x0f = floorf(px), y0f = floorf(py);
      float wx1 = px - x0f, wy1 = py - y0f;
      int x0 = (int)x0f, y0 = (int)y0f;
#pragma unroll
      for (int dy = 0; dy < 2; ++dy) {
        int yi = y0 + dy;
        bool vy = (yi >= 0) & (yi < Wl[lvl]);
        int yc = min(max(yi, 0), Wl[lvl] - 1);
        float wy = dy ? wy1 : 1.f - wy1;
#pragma unroll
        for (int dx = 0; dx < 2; ++dx) {
          int xi = x0 + dx;
          bool vx = (xi >= 0) & (xi < Wl[lvl]);
          int xc = min(max(xi, 0), Wl[lvl] - 1);
          float cw = (vx & vy) ? aw * wy * (dx ? wx1 : 1.f - wx1) : 0.f;
          bf16x8 v = *(const bf16x8*)(vbase + (size_t)(st[lvl] + yc * Wl[lvl] + xc) * 256);
#pragma unroll
          for (int j = 0; j < 8; ++j) acc[j] += cw * (float)v[j];
        }
      }
    }
  }
  bf16x8 o;
#pragma unroll
  for (int j = 0; j < 8; ++j) o[j] = (bf16_t)acc[j];
  *(bf16x8*)(core + (size_t)bq * 256 + h * 32 + d0) = o;
}

// out = LN(a + res [+ eb]) * g + beta ; one row per wave
template <typename TA, typename TR, typename TO>
__global__ __launch_bounds__(256) void k_ln4(
    const TA* __restrict__ a, const TR* __restrict__ res,
    const float* __restrict__ eb, const float* __restrict__ g,
    const float* __restrict__ beta, TO* __restrict__ out, int rows)
{
  const int wave = threadIdx.x >> 6, lane = threadIdx.x & 63;
  const int row = blockIdx.x * 4 + wave;
  if (row >= rows) return;
  const size_t base = (size_t)row * 256 + lane * 4;
  float v[4];
#pragma unroll
  for (int j = 0; j < 4; ++j) {
    v[j] = (float)a[base + j] + (float)res[base + j];
    if (eb) v[j] += eb[lane * 4 + j];
  }
  float s1 = v[0] + v[1] + v[2] + v[3];
  float s2 = v[0] * v[0] + v[1] * v[1] + v[2] * v[2] + v[3] * v[3];
#pragma unroll
  for (int o = 32; o > 0; o >>= 1) { s1 += __shfl_xor(s1, o); s2 += __shfl_xor(s2, o); }
  float m = s1 * (1.f / 256.f);
  float var = s2 * (1.f / 256.f) - m * m;
  float inv = rsqrtf(var + 1e-5f);
#pragma unroll
  for (int j = 0; j < 4; ++j)
    out[base + j] = (TO)(((v[j] - m) * inv) * g[lane * 4 + j] + beta[lane * 4 + j]);
}

// ---------------- launcher ----------------
extern "C" void kernel_launch(void* const* d_in, const int* in_sizes, int n_in,
                              void* d_out, int out_size, void* d_ws, size_t ws_size,
                              hipStream_t stream) {
  const float* src   = (const float*)d_in[0];
  const float* pos   = (const float*)d_in[1];
  const float* rp    = (const float*)d_in[2];
  const float* W_off = (const float*)d_in[5];
  const float* b_off = (const float*)d_in[6];
  const float* W_attn= (const float*)d_in[7];
  const float* b_attn= (const float*)d_in[8];
  const float* W_val = (const float*)d_in[9];
  const float* b_val = (const float*)d_in[10];
  const float* W_out = (const float*)d_in[11];
  const float* b_out = (const float*)d_in[12];
  const float* g1    = (const float*)d_in[13];
  const float* beta1 = (const float*)d_in[14];
  const float* W1    = (const float*)d_in[15];
  const float* bl1   = (const float*)d_in[16];
  const float* W2    = (const float*)d_in[17];
  const float* bl2   = (const float*)d_in[18];
  const float* g2    = (const float*)d_in[19];
  const float* beta2 = (const float*)d_in[20];

  char* ws = (char*)d_ws;
  const size_t SZ_TOK = (size_t)M_ * 256 * 2;  // 27,326,464
  const size_t SZ_ATT = (size_t)M_ * 160 * 4;  // 34,158,080

  size_t o = 0;
  bf16_t* wTqkv = (bf16_t*)(ws + o); o += 480 * 256 * 2;
  bf16_t* wTval = (bf16_t*)(ws + o); o += 256 * 256 * 2;
  bf16_t* wTout = (bf16_t*)(ws + o); o += 256 * 256 * 2;
  bf16_t* wT1   = (bf16_t*)(ws + o); o += 2048 * 256 * 2;
  bf16_t* wT2   = (bf16_t*)(ws + o); o += 2048 * 256 * 2;
  o = (o + 255) & ~(size_t)255;
  char* Areg = ws + o; o += SZ_TOK;   // coreb
  char* Creg = ws + o; o += SZ_ATT;   // attnb -> attn_out
  char* Dreg = ws + o; o += SZ_TOK;   // valb -> xbuf

  bf16_t* coreb   = (bf16_t*)Areg;
  float*  attnb   = (float*) Creg;
  bf16_t* attn_out= (bf16_t*)Creg;
  bf16_t* valb    = (bf16_t*)Dreg;
  bf16_t* xbuf    = (bf16_t*)Dreg;
  bf16_t* offb    = (bf16_t*)d_out;   // dead before k_ffn writes outf
  float*  outf    = (float*) d_out;

  k_transpose_all<<<dim3(1272), 256, 0, stream>>>(
      W_off, W_attn, W_val, W_out, W1, W2,
      wTqkv, wTqkv + 320 * 256, wTval, wTout, wT1, wT2);

  dim3 blk(256);
  const int gM = (M_ + BM - 1) / BM;   // 417

  gemm_qkv<<<dim3(gM * 4), blk, 0, stream>>>(src, pos, wTqkv, b_off, b_attn, offb, attnb);
  gemm_bt<MODE_BF16, true><<<dim3(gM * 2), blk, 0, stream>>>(src, 256, wTval, 256, b_val, valb, 256, M_, 256, 256);
  k_sample<<<dim3((M_ + 7) / 8), blk, 0, stream>>>(valb, offb, attnb, rp, coreb);
  gemm_bt<MODE_BF16, false><<<dim3(gM * 2), blk, 0, stream>>>(coreb, 256, wTout, 256, b_out, attn_out, 256, M_, 256, 256);
  k_ln4<float, bf16_t, bf16_t><<<dim3((M_ + 3) / 4), blk, 0, stream>>>(src, attn_out, (const float*)nullptr, g1, beta1, xbuf, M_);

  k_ffn<<<dim3((M_ + 63) / 64), blk, 0, stream>>>(xbuf, wT1, bl1, wT2, outf);

  k_ln4<bf16_t, float, float><<<dim3((M_ + 3) / 4), blk, 0, stream>>>(xbuf, outf, bl2, g2, beta2, outf, M_);
}